// Round 5
// baseline (2368.194 us; speedup 1.0000x reference)
//
#include <hip/hip_runtime.h>

#define CH    256
#define MEM   684
#define POSN  128
#define NEGN  512
#define CLS   60
#define ROWS  41040
#define BATCHN 512

#define T1F 0.09375f   // hard-neg pre-filter (c > T1), ~6.7% pass
#define T0F 0.03125f   // rand pre-filter (r < T0), ~3.1% pass
#define CAPCL 4096     // per-row c-candidate cap (E~2700, sd~50)
#define CAPRL 2048     // per-row r-candidate cap (E~1261, sd~35)
#define CSTG  48       // per-block-row LDS stage cap in gemm (E~8.5)

typedef unsigned int u32;
typedef unsigned short u16;
typedef unsigned long long u64;

typedef __attribute__((ext_vector_type(8))) short bf16x8;
typedef __attribute__((ext_vector_type(4))) float f32x4;

__device__ __forceinline__ float b2f(u16 u) { return __uint_as_float(((u32)u) << 16); }
__device__ __forceinline__ u16 f2b(float x) {
  u32 u = __float_as_uint(x);
  u32 r = ((u >> 16) & 1u) + 0x7FFFu;
  return (u16)((u + r) >> 16);
}
__device__ __forceinline__ u32 umin2(u32 a, u32 b) { return a < b ? a : b; }

#if defined(__has_builtin)
#if __has_builtin(__builtin_amdgcn_global_load_lds)
#define HAVE_GLL 1
#endif
#endif

__device__ __forceinline__ void stage16(const u16* g, u16* l) {
#ifdef HAVE_GLL
  __builtin_amdgcn_global_load_lds((const __attribute__((address_space(1))) void*)g,
                                   (__attribute__((address_space(3))) void*)l, 16, 0, 0);
#else
  *(uint4*)l = *(const uint4*)g;
#endif
}

__device__ __forceinline__ void cvt8(const float* sp, u16* dp) {
  float4 a = *(const float4*)(sp);
  float4 b = *(const float4*)(sp + 4);
  uint4 o;
  o.x = (u32)f2b(a.x) | ((u32)f2b(a.y) << 16);
  o.y = (u32)f2b(a.z) | ((u32)f2b(a.w) << 16);
  o.z = (u32)f2b(b.x) | ((u32)f2b(b.y) << 16);
  o.w = (u32)f2b(b.z) | ((u32)f2b(b.w) << 16);
  *(uint4*)(dp) = o;
}

// ---------------- K1: fused convert(+scatter substitution) + fB + zeroing ----------------
// blocks [0,5130): bankB rows (8/block), substituting f rows at enq positions
// blocks [5130,5194): fB rows (8/block)
// block 5194: zero gccnt + out
__global__ __launch_bounds__(256) void k_prep(const float* __restrict__ bank,
                                              const float* __restrict__ f,
                                              const int* __restrict__ enq,
                                              u16* __restrict__ bankB,
                                              u16* __restrict__ fB,
                                              u32* __restrict__ gccnt,
                                              float* __restrict__ out) {
  __shared__ int rowsrc[8];
  const int b = blockIdx.x;
  const int tid = threadIdx.x;
  if (b < 5130) {
    if (tid < 8) rowsrc[tid] = -1;
    __syncthreads();
    int r0 = b * 8;
#pragma unroll
    for (int e = 0; e < 2; e++) {
      int idx = tid * 2 + e;
      int v = enq[idx];
      if (v >= r0 && v < r0 + 8) atomicMax(&rowsrc[v - r0], idx);  // last-write-wins = max n
    }
    __syncthreads();
    int sub = tid >> 5, ch = (tid & 31) * 8;
    int row = r0 + sub;
    int src = rowsrc[sub];
    const float* sp = (src >= 0) ? (f + (size_t)src * CH + ch) : (bank + (size_t)row * CH + ch);
    cvt8(sp, bankB + (size_t)row * CH + ch);
  } else if (b < 5194) {
    int idx = b - 5130;
    int nrow = idx * 8 + (tid >> 5);
    int ch = (tid & 31) * 8;
    cvt8(f + (size_t)nrow * CH + ch, fB + (size_t)nrow * CH + ch);
  } else {
    if (tid < 512) gccnt[tid] = 0;
    if (tid == 0) out[0] = 0.0f;
  }
}

// wave-aggregated LDS list append; returns slot for pred lanes
__device__ __forceinline__ u32 wave_append(u32* cnt, bool pred) {
  u64 mask = __ballot(pred);
  u32 ret = 0xFFFFFFFFu;
  if (pred) {
    int lane = (int)(threadIdx.x & 63);
    int leader = __ffsll((u64)mask) - 1;
    u32 base = 0;
    if (lane == leader) base = atomicAdd(cnt, (u32)__popcll(mask));
    base = __shfl(base, leader, 64);
    ret = base + (u32)__popcll(mask & ((1ull << lane) - 1ull));
  }
  return ret;
}

// ---------------- K2: rand pre-filter: per-row (r,m) pairs with r < T0 ----------------
#define VITER 5
#define VTAIL 80
#define VTAILBASE 40960

__global__ __launch_bounds__(1024) void k_rfilter(const float* __restrict__ rnd,
                                                  const int* __restrict__ label,
                                                  float* __restrict__ grl,
                                                  u32* __restrict__ grcnt) {
  const int n = blockIdx.x;
  const int tid = threadIdx.x;
  const float* rrow = rnd + (size_t)n * ROWS;
  const int lab = label[n];
  __shared__ u32 cnt;
  if (tid == 0) cnt = 0;
  __syncthreads();
  float* outbase = grl + (size_t)n * CAPRL * 2;
  int rb = (tid * 8) % 60;
  for (int it = 0; it < VITER; it++) {
    int m8 = (it * 1024 + tid) * 8;
    float4 a = *(const float4*)(rrow + m8);
    float4 b = *(const float4*)(rrow + m8 + 4);
    float rs[8] = {a.x, a.y, a.z, a.w, b.x, b.y, b.z, b.w};
    int r = rb;
#pragma unroll
    for (int j = 0; j < 8; j++) {
      bool pred = (r != lab) && (rs[j] < T0F);
      u32 slot = wave_append(&cnt, pred);
      if (pred && slot < CAPRL) {
        float2 p;
        p.x = rs[j];
        p.y = __uint_as_float((u32)(m8 + j));
        *(float2*)(outbase + slot * 2) = p;
      }
      r++;
      if (r == 60) r = 0;
    }
    rb += 32;  // 8192 % 60
    if (rb >= 60) rb -= 60;
  }
  if (tid < VTAIL) {
    int m = VTAILBASE + tid;
    int r = 40 + tid;  // 40960 % 60 = 40
    if (r >= 60) r -= 60;
    float rv = rrow[m];
    bool pred = (r != lab) && (rv < T0F);
    u32 slot = wave_append(&cnt, pred);
    if (pred && slot < CAPRL) {
      float2 p;
      p.x = rv;
      p.y = __uint_as_float((u32)m);
      *(float2*)(outbase + slot * 2) = p;
    }
  }
  __syncthreads();
  if (tid == 0) grcnt[n] = cnt;  // true count (may exceed CAPRL -> select fallback)
}

// ---------------- K3: bf16 MFMA GEMM, NO Cb -> candidates + positives only ----------------
__global__ __launch_bounds__(256) void k_gemm(const u16* __restrict__ fB,
                                              const u16* __restrict__ bankB,
                                              const int* __restrict__ label,
                                              float* __restrict__ gclist,
                                              u32* __restrict__ gccnt,
                                              u16* __restrict__ gpos) {
  __shared__ __align__(16) u16 As[128 * 32];
  __shared__ __align__(16) u16 Bs[128 * 32];
  __shared__ float cstage[128 * CSTG];
  __shared__ u32 ccnt_l[128];
  __shared__ int lab_l[128];
  const int tid = threadIdx.x;
  const int wave = tid >> 6, lane = tid & 63;
  const int bm = blockIdx.x * 128;
  const int bn = blockIdx.y * 128;
  const int wm = (wave & 1) * 64, wn = (wave >> 1) * 64;
  const int m_in = lane & 15;
  const int ks = (lane >> 4) * 8;

  if (tid < 128) { ccnt_l[tid] = 0; lab_l[tid] = label[bm + tid]; }

  f32x4 acc[4][4] = {};

  for (int k0 = 0; k0 < CH; k0 += 32) {
    __syncthreads();
#pragma unroll
    for (int i = 0; i < 2; i++) {
      int u = tid + 256 * i;
      int row = u >> 2;
      int kk = (u & 3) * 8;
      stage16(fB + (size_t)(bm + row) * CH + k0 + kk, As + u * 8);
      int rb = bn + row;
      if (rb >= ROWS) rb = bn;
      stage16(bankB + (size_t)rb * CH + k0 + kk, Bs + u * 8);
    }
    __syncthreads();

    bf16x8 af[4], bf[4];
#pragma unroll
    for (int t4 = 0; t4 < 4; t4++) {
      af[t4] = *(const bf16x8*)(As + (wm + t4 * 16 + m_in) * 32 + ks);
      bf[t4] = *(const bf16x8*)(Bs + (wn + t4 * 16 + m_in) * 32 + ks);
    }
#pragma unroll
    for (int mi = 0; mi < 4; mi++)
#pragma unroll
      for (int ni = 0; ni < 4; ni++)
        acc[mi][ni] = __builtin_amdgcn_mfma_f32_16x16x32_bf16(af[mi], bf[ni], acc[mi][ni], 0, 0, 0);
  }

  const int rr = (lane >> 4) * 4;
  const int cc = lane & 15;
#pragma unroll
  for (int ni = 0; ni < 4; ni++) {
    int ncol = bn + wn + ni * 16 + cc;
    if (ncol >= ROWS) continue;
    int jdiv = ncol / 60;
    int ncolmod = ncol - jdiv * 60;
#pragma unroll
    for (int mi = 0; mi < 4; mi++) {
      int rloc = wm + mi * 16 + rr;
#pragma unroll
      for (int q = 0; q < 4; q++) {
        int rq = rloc + q;
        u16 cw = f2b(acc[mi][ni][q]);
        float c = b2f(cw);
        if (ncolmod == lab_l[rq]) {
          gpos[(size_t)(bm + rq) * MEM + jdiv] = cw;  // positive: direct write
        } else if (c > T1F) {
          u32 slot = atomicAdd(&ccnt_l[rq], 1u);
          if (slot < CSTG) {
            cstage[rq * CSTG + slot] = c;
          } else {  // near-impossible spill path, still exact
            int grow = bm + rq;
            u32 s2 = atomicAdd(&gccnt[grow], 1u);
            if (s2 < CAPCL) gclist[(size_t)grow * CAPCL + s2] = c;
          }
        }
      }
    }
  }
  __syncthreads();
  if (tid < 128) {
    u32 k = umin2(ccnt_l[tid], CSTG);
    if (k) {
      int grow = bm + tid;
      u32 base = atomicAdd(&gccnt[grow], k);
      for (u32 i = 0; i < k; i++) {
        u32 s = base + i;
        if (s < CAPCL) gclist[(size_t)grow * CAPCL + s] = cstage[tid * CSTG + i];
      }
    }
  }
}

// ---------------- block helpers (1024 threads, shfl-based) ----------------
__device__ __forceinline__ u32 scanN(u32 v, u32* tmp, int tid) {
  u32 x = v;
#pragma unroll
  for (int off = 1; off < 64; off <<= 1) {
    u32 y = (u32)__shfl_up((int)x, off, 64);
    if ((tid & 63) >= off) x += y;
  }
  if ((tid & 63) == 63) tmp[tid >> 6] = x;
  __syncthreads();
  if (tid < 64) {
    u32 t = (tid < 16) ? tmp[tid] : 0u;
#pragma unroll
    for (int off = 1; off < 16; off <<= 1) {
      u32 y = (u32)__shfl_up((int)t, off, 64);
      if (tid >= off) t += y;
    }
    if (tid < 16) tmp[tid + 16] = t;
  }
  __syncthreads();
  u32 base = (tid >= 64) ? tmp[16 + (tid >> 6) - 1] : 0u;
  return base + x;
}

__device__ __forceinline__ float redsum1024(float v, float* tmp, int tid) {
#pragma unroll
  for (int off = 32; off > 0; off >>= 1) v += __shfl_xor(v, off, 64);
  if ((tid & 63) == 0) tmp[tid >> 6] = v;
  __syncthreads();
  if (tid < 64) {
    float t = (tid < 16) ? tmp[tid] : 0.f;
#pragma unroll
    for (int off = 8; off > 0; off >>= 1) t += __shfl_xor(t, off, 64);
    if (tid == 0) tmp[0] = t;
  }
  __syncthreads();
  float r = tmp[0];
  __syncthreads();
  return r;
}

__device__ __forceinline__ int binof(float v, float lo, float scale) {
  int b = (int)((v - lo) * scale);
  return b < 0 ? 0 : (b > 2047 ? 2047 : b);
}

// bf16-input fp32-acc dot of f_l (LDS, fp32) with bankB row m
__device__ __forceinline__ float dotm(const float* f_l, const u16* brow) {
  float a0 = 0.f, a1 = 0.f, a2 = 0.f, a3 = 0.f;
#pragma unroll
  for (int k = 0; k < CH; k += 8) {
    uint4 w = *(const uint4*)(brow + k);
    float4 fa = *(const float4*)(f_l + k);
    float4 fb = *(const float4*)(f_l + k + 4);
    a0 += fa.x * b2f((u16)w.x) + fa.y * b2f((u16)(w.x >> 16));
    a1 += fa.z * b2f((u16)w.y) + fa.w * b2f((u16)(w.y >> 16));
    a2 += fb.x * b2f((u16)w.z) + fb.y * b2f((u16)(w.z >> 16));
    a3 += fb.z * b2f((u16)w.w) + fb.w * b2f((u16)(w.w >> 16));
  }
  return (a0 + a1) + (a2 + a3);
}

// ---------------- K4: per-row selection + loss (lists only; no Cb) ----------------
__global__ __launch_bounds__(1024) void k_select(const int* __restrict__ label,
                                                 const float* __restrict__ gclist,
                                                 const u32* __restrict__ gccnt,
                                                 const float* __restrict__ grl,
                                                 const u32* __restrict__ grcnt,
                                                 const u16* __restrict__ gpos,
                                                 const u16* __restrict__ fB,
                                                 const u16* __restrict__ bankB,
                                                 const float* __restrict__ rnd,
                                                 float* __restrict__ out) {
  const int n = blockIdx.x;
  const int tid = threadIdx.x;
  const int lab = label[n];

  __shared__ __align__(16) char smem[56576];
  u32* histc = (u32*)(smem);               // 2048
  u32* histr = (u32*)(smem + 8192);        // 2048
  float* cl = (float*)(smem + 16384);      // 4096 (posv aliases)
  float* rl_rv = (float*)(smem + 32768);   // 2048
  u32* rl_mi = (u32*)(smem + 40960);       // 2048
  u32* wl = (u32*)(smem + 49152);          // 512
  float* cb_c = (float*)(smem + 51200);    // 512
  float* rb_r = (float*)(smem + 53248);    // 256
  u32* rb_m = (u32*)(smem + 54272);        // 256
  float* f_l = (float*)(smem + 55296);     // 256
  u32* stmp = (u32*)(smem + 56320);        // 32
  float* fred = (float*)(smem + 56448);    // 16
  u32* ctl = (u32*)(smem + 56512);         // 16
  float* bcf = (float*)(ctl + 8);
  float* posv = cl;

  const u32 Fg = gccnt[n];
  const u32 Gg = grcnt[n];
  const bool cok = (Fg >= NEGN && Fg <= CAPCL);
  const bool rok = (Gg >= NEGN && Gg <= CAPRL);
  const float T1e = cok ? T1F : -1.1f;
  const float sc_c = 2048.0f / (cok ? (1.0625f - T1F) : 2.2f);
  const float sc_r = 2048.0f / (rok ? T0F : 1.0625f);

  for (int i = tid; i < 2048; i += 1024) { histc[i] = 0; histr[i] = 0; }
  if (tid < 16) ctl[tid] = 0;
  if (tid < 256) f_l[tid] = b2f(fB[(size_t)n * CH + tid]);
  __syncthreads();

  // ---- histograms ----
  if (cok) {
    for (u32 i = tid; i < Fg; i += 1024) {
      float c = gclist[(size_t)n * CAPCL + i];
      cl[i] = c;
      atomicAdd(&histc[binof(c, T1e, sc_c)], 1u);
    }
  } else {  // cold exact fallback: recompute all dots
    for (int m = tid; m < ROWS; m += 1024) {
      if (m % 60 == lab) continue;
      float c = b2f(f2b(dotm(f_l, bankB + (size_t)m * CH)));
      atomicAdd(&histc[binof(c, T1e, sc_c)], 1u);
    }
  }
  if (rok) {
    const float* rbase = grl + (size_t)n * CAPRL * 2;
    for (u32 i = tid; i < Gg; i += 1024) {
      float2 p = *(const float2*)(rbase + i * 2);
      rl_rv[i] = p.x;
      rl_mi[i] = __float_as_uint(p.y);
      atomicAdd(&histr[binof(p.x, 0.0f, sc_r)], 1u);
    }
  } else {  // cold fallback: full rnd rescan
    const float* rrow = rnd + (size_t)n * ROWS;
    for (int m = tid; m < ROWS; m += 1024) {
      if (m % 60 == lab) continue;
      atomicAdd(&histr[binof(rrow[m], 0.0f, sc_r)], 1u);
    }
  }
  __syncthreads();

  // ---- boundary c (descending top-NEGN) ----
  u32 fsum = histc[tid * 2] + histc[tid * 2 + 1];
  u32 finc = scanN(fsum, stmp, tid);
  u32 F = stmp[31];
  u32 fexc = finc - fsum;
  u32 tcpos = F - NEGN + 1;
  if (fexc < tcpos && tcpos <= finc) {
    u32 run = fexc;
#pragma unroll
    for (int i = 0; i < 2; i++) {
      u32 h = histc[tid * 2 + i];
      if (run + h >= tcpos) { ctl[2] = (u32)(tid * 2 + i); ctl[3] = F - (run + h); break; }
      run += h;
    }
  }
  // ---- boundary r (ascending bottom-NEGN) ----
  u32 gsum = histr[tid * 2] + histr[tid * 2 + 1];
  u32 ginc = scanN(gsum, stmp, tid);
  u32 gexc = ginc - gsum;
  if (gexc < NEGN && NEGN <= ginc) {
    u32 run = gexc;
#pragma unroll
    for (int i = 0; i < 2; i++) {
      u32 h = histr[tid * 2 + i];
      if (run + h >= NEGN) { ctl[4] = (u32)(tid * 2 + i); ctl[5] = run; break; }
      run += h;
    }
  }
  __syncthreads();
  const u32 b_c = ctl[2], cnt_gt = ctl[3];
  const u32 b_r = ctl[4], cnt_lt = ctl[5];
  const u32 need_c = NEGN - cnt_gt;
  const u32 need_r = NEGN - cnt_lt;

  // ---- phase B: c exp-sums + c-boundary list; r winner list + r-boundary list ----
  float sH = 0.f;
  if (cok) {
    for (u32 i = tid; i < Fg; i += 1024) {
      float c = cl[i];
      u32 b = (u32)binof(c, T1e, sc_c);
      if (b > b_c) sH += expf(c);
      else if (b == b_c) {
        u32 id = atomicAdd(&ctl[0], 1u);
        if (id < 512) cb_c[id] = c;
      }
    }
  } else {
    for (int m = tid; m < ROWS; m += 1024) {
      if (m % 60 == lab) continue;
      float c = b2f(f2b(dotm(f_l, bankB + (size_t)m * CH)));
      u32 b = (u32)binof(c, T1e, sc_c);
      if (b > b_c) sH += expf(c);
      else if (b == b_c) {
        u32 id = atomicAdd(&ctl[0], 1u);
        if (id < 512) cb_c[id] = c;
      }
    }
  }
  if (rok) {
    for (u32 i = tid; i < Gg; i += 1024) {
      float rv = rl_rv[i];
      u32 b = (u32)binof(rv, 0.0f, sc_r);
      if (b < b_r) {
        u32 id = atomicAdd(&ctl[6], 1u);
        wl[id] = rl_mi[i];  // id < cnt_lt <= 511
      } else if (b == b_r) {
        u32 id = atomicAdd(&ctl[1], 1u);
        if (id < 256) { rb_r[id] = rv; rb_m[id] = rl_mi[i]; }
      }
    }
  } else {
    const float* rrow = rnd + (size_t)n * ROWS;
    for (int m = tid; m < ROWS; m += 1024) {
      if (m % 60 == lab) continue;
      float rv = rrow[m];
      u32 b = (u32)binof(rv, 0.0f, sc_r);
      if (b < b_r) {
        u32 id = atomicAdd(&ctl[6], 1u);
        if (id < 512) wl[id] = (u32)m;
      } else if (b == b_r) {
        u32 id = atomicAdd(&ctl[1], 1u);
        if (id < 256) { rb_r[id] = rv; rb_m[id] = (u32)m; }
      }
    }
  }
  __syncthreads();
  float SHsum = redsum1024(sH, fred, tid);

  if (tid == 0) {
    // c boundary bin: take need_c LARGEST values
    float addH = 0.f;
    u32 Lc = umin2(ctl[0], 512u);
    u32 kc = umin2(need_c, Lc);
    for (u32 k = 0; k < kc; k++) {
      int best = 0;
      float bv = -3.0e38f;
      for (u32 i = 0; i < Lc; i++)
        if (cb_c[i] > bv) { bv = cb_c[i]; best = (int)i; }
      cb_c[best] = -3.0e38f;
      addH += expf(bv);
    }
    bcf[0] = addH;
    // rand boundary bin: stable order = (rand value, index) ascending; append winners
    u32 Lr = umin2(ctl[1], 256u);
    for (u32 i = 1; i < Lr; i++) {
      float rv = rb_r[i]; u32 mm = rb_m[i];
      int j = (int)i - 1;
      while (j >= 0 && (rb_r[j] > rv || (rb_r[j] == rv && rb_m[j] > mm))) {
        rb_r[j + 1] = rb_r[j]; rb_m[j + 1] = rb_m[j];
        j--;
      }
      rb_r[j + 1] = rv; rb_m[j + 1] = mm;
    }
    u32 kr = umin2(need_r, Lr);
    u32 base = ctl[6];
    for (u32 i = 0; i < kr; i++)
      if (base + i < 512) wl[base + i] = rb_m[i];
    ctl[7] = umin2(base + kr, 512u);  // winner count (==512 on hot path)
  }
  __syncthreads();

  // ---- winner dots -> S_R ----
  float sR = 0.f;
  if (tid < (int)ctl[7]) {
    u32 m = wl[tid];
    float c = b2f(f2b(dotm(f_l, bankB + (size_t)m * CH)));
    sR = expf(c);
  }
  float SRsum = redsum1024(sR, fred, tid);
  const float S_H = SHsum + bcf[0];
  const float S_R = SRsum;
  __syncthreads();  // cl reads complete before posv (alias) overwrite

  // ---- positives: 684 from gpos, 128 smallest via register bitonic ----
  float v = (tid < MEM) ? b2f(gpos[(size_t)n * MEM + tid]) : INFINITY;
  for (u32 k = 2; k <= 1024; k <<= 1) {
    for (u32 j = k >> 1; j > 0; j >>= 1) {
      bool up = ((tid & k) == 0);
      float pv;
      if (j >= 64) {
        posv[tid] = v;
        __syncthreads();
        pv = posv[tid ^ j];
        __syncthreads();
      } else {
        pv = __shfl_xor(v, (int)j, 64);
      }
      bool lower = ((tid & j) == 0);
      float mn = fminf(v, pv), mx = fmaxf(v, pv);
      v = (lower == up) ? mn : mx;
    }
  }

  float term = 0.f;
  if (tid < POSN) {
    float p = v;
    float e = expf(p);
    term = (p - logf(e + S_H)) + (p - logf(e + S_R));
  }
  float tot = redsum1024(term, fred, tid);
  if (tid == 0) atomicAdd(out, -tot / (float)(BATCHN * 2 * POSN));
}

extern "C" void kernel_launch(void* const* d_in, const int* in_sizes, int n_in,
                              void* d_out, int out_size, void* d_ws, size_t ws_size,
                              hipStream_t stream) {
  const float* f = (const float*)d_in[0];
  const int* label = (const int*)d_in[1];
  const int* enq = (const int*)d_in[2];
  const float* bank = (const float*)d_in[3];
  const float* rnd = (const float*)d_in[5];
  float* out = (float*)d_out;

  // workspace layout (~38.8 MB)
  char* ws = (char*)d_ws;
  u16* bankB = (u16*)ws;                        // 21,012,480
  u16* fB = (u16*)(ws + 21012480);              //    262,144
  float* gclist = (float*)(ws + 21274624);      // 512*4096*4 = 8,388,608
  float* grl = (float*)(ws + 29663232);         // 512*2048*8 = 8,388,608
  u16* gpos = (u16*)(ws + 38051840);            // 512*684*2  =   700,416
  u32* gccnt = (u32*)(ws + 38752256);           // 2048
  u32* grcnt = (u32*)(ws + 38754304);           // 2048

  k_prep<<<dim3(5195), dim3(256), 0, stream>>>(bank, f, enq, bankB, fB, gccnt, out);
  k_rfilter<<<dim3(BATCHN), dim3(1024), 0, stream>>>(rnd, label, grl, grcnt);
  k_gemm<<<dim3(4, 321), dim3(256), 0, stream>>>(fB, bankB, label, gclist, gccnt, gpos);
  k_select<<<dim3(BATCHN), dim3(1024), 0, stream>>>(label, gclist, gccnt, grl, grcnt, gpos,
                                                    fB, bankB, rnd, out);
}

// Round 6
// 272.975 us; speedup vs baseline: 8.6755x; 8.6755x over previous
//
#include <hip/hip_runtime.h>

#define CH    256
#define MEM   684
#define POSN  128
#define NEGN  512
#define CLS   60
#define ROWS  41040
#define BATCHN 512

#define T1F 0.09375f   // hard-neg pre-filter (c > T1), ~6.7% pass
#define T0F 0.03125f   // rand pre-filter (r < T0), ~3.1% pass
#define CAPCL 4096     // per-row c-candidate cap (E~2700, sd~50)
#define CAPRL 2048     // per-row r-candidate cap (E~1261, sd~35)
#define CSTG  48       // per-block-row LDS stage cap in gemm (E~8.5)

typedef unsigned int u32;
typedef unsigned short u16;
typedef unsigned long long u64;

typedef __attribute__((ext_vector_type(8))) short bf16x8;
typedef __attribute__((ext_vector_type(4))) float f32x4;

__device__ __forceinline__ float b2f(u16 u) { return __uint_as_float(((u32)u) << 16); }
__device__ __forceinline__ u16 f2b(float x) {
  u32 u = __float_as_uint(x);
  u32 r = ((u >> 16) & 1u) + 0x7FFFu;
  return (u16)((u + r) >> 16);
}
__device__ __forceinline__ u32 umin2(u32 a, u32 b) { return a < b ? a : b; }

#if defined(__has_builtin)
#if __has_builtin(__builtin_amdgcn_global_load_lds)
#define HAVE_GLL 1
#endif
#endif

__device__ __forceinline__ void stage16(const u16* g, u16* l) {
#ifdef HAVE_GLL
  __builtin_amdgcn_global_load_lds((const __attribute__((address_space(1))) void*)g,
                                   (__attribute__((address_space(3))) void*)l, 16, 0, 0);
#else
  *(uint4*)l = *(const uint4*)g;
#endif
}

__device__ __forceinline__ void cvt8(const float* sp, u16* dp) {
  float4 a = *(const float4*)(sp);
  float4 b = *(const float4*)(sp + 4);
  uint4 o;
  o.x = (u32)f2b(a.x) | ((u32)f2b(a.y) << 16);
  o.y = (u32)f2b(a.z) | ((u32)f2b(a.w) << 16);
  o.z = (u32)f2b(b.x) | ((u32)f2b(b.y) << 16);
  o.w = (u32)f2b(b.z) | ((u32)f2b(b.w) << 16);
  *(uint4*)(dp) = o;
}

// ---------------- K1: fused convert(+scatter substitution) + fB + zeroing ----------------
// blocks [0,5130): bankB rows (8/block), substituting f rows at enq positions
// blocks [5130,5194): fB rows (8/block)
// block 5194: zero gccnt (ALL 512 — R5 bug: tid<512 with 256 threads) + out
__global__ __launch_bounds__(256) void k_prep(const float* __restrict__ bank,
                                              const float* __restrict__ f,
                                              const int* __restrict__ enq,
                                              u16* __restrict__ bankB,
                                              u16* __restrict__ fB,
                                              u32* __restrict__ gccnt,
                                              float* __restrict__ out) {
  __shared__ int rowsrc[8];
  const int b = blockIdx.x;
  const int tid = threadIdx.x;
  if (b < 5130) {
    if (tid < 8) rowsrc[tid] = -1;
    __syncthreads();
    int r0 = b * 8;
#pragma unroll
    for (int e = 0; e < 2; e++) {
      int idx = tid * 2 + e;
      int v = enq[idx];
      if (v >= r0 && v < r0 + 8) atomicMax(&rowsrc[v - r0], idx);  // last-write-wins = max n
    }
    __syncthreads();
    int sub = tid >> 5, ch = (tid & 31) * 8;
    int row = r0 + sub;
    int src = rowsrc[sub];
    const float* sp = (src >= 0) ? (f + (size_t)src * CH + ch) : (bank + (size_t)row * CH + ch);
    cvt8(sp, bankB + (size_t)row * CH + ch);
  } else if (b < 5194) {
    int idx = b - 5130;
    int nrow = idx * 8 + (tid >> 5);
    int ch = (tid & 31) * 8;
    cvt8(f + (size_t)nrow * CH + ch, fB + (size_t)nrow * CH + ch);
  } else {
    for (int i = tid; i < BATCHN; i += 256) gccnt[i] = 0;  // FIX: cover all 512
    if (tid == 0) out[0] = 0.0f;
  }
}

// wave-aggregated LDS list append; returns slot for pred lanes
__device__ __forceinline__ u32 wave_append(u32* cnt, bool pred) {
  u64 mask = __ballot(pred);
  u32 ret = 0xFFFFFFFFu;
  if (pred) {
    int lane = (int)(threadIdx.x & 63);
    int leader = __ffsll((u64)mask) - 1;
    u32 base = 0;
    if (lane == leader) base = atomicAdd(cnt, (u32)__popcll(mask));
    base = __shfl(base, leader, 64);
    ret = base + (u32)__popcll(mask & ((1ull << lane) - 1ull));
  }
  return ret;
}

// ---------------- K2: rand pre-filter: per-row (r,m) pairs with r < T0 ----------------
#define VITER 5
#define VTAIL 80
#define VTAILBASE 40960

__global__ __launch_bounds__(1024) void k_rfilter(const float* __restrict__ rnd,
                                                  const int* __restrict__ label,
                                                  float* __restrict__ grl,
                                                  u32* __restrict__ grcnt) {
  const int n = blockIdx.x;
  const int tid = threadIdx.x;
  const float* rrow = rnd + (size_t)n * ROWS;
  const int lab = label[n];
  __shared__ u32 cnt;
  if (tid == 0) cnt = 0;
  __syncthreads();
  float* outbase = grl + (size_t)n * CAPRL * 2;
  int rb = (tid * 8) % 60;
  for (int it = 0; it < VITER; it++) {
    int m8 = (it * 1024 + tid) * 8;
    float4 a = *(const float4*)(rrow + m8);
    float4 b = *(const float4*)(rrow + m8 + 4);
    float rs[8] = {a.x, a.y, a.z, a.w, b.x, b.y, b.z, b.w};
    int r = rb;
#pragma unroll
    for (int j = 0; j < 8; j++) {
      bool pred = (r != lab) && (rs[j] < T0F);
      u32 slot = wave_append(&cnt, pred);
      if (pred && slot < CAPRL) {
        float2 p;
        p.x = rs[j];
        p.y = __uint_as_float((u32)(m8 + j));
        *(float2*)(outbase + slot * 2) = p;
      }
      r++;
      if (r == 60) r = 0;
    }
    rb += 32;  // 8192 % 60
    if (rb >= 60) rb -= 60;
  }
  if (tid < VTAIL) {
    int m = VTAILBASE + tid;
    int r = 40 + tid;  // 40960 % 60 = 40
    if (r >= 60) r -= 60;
    float rv = rrow[m];
    bool pred = (r != lab) && (rv < T0F);
    u32 slot = wave_append(&cnt, pred);
    if (pred && slot < CAPRL) {
      float2 p;
      p.x = rv;
      p.y = __uint_as_float((u32)m);
      *(float2*)(outbase + slot * 2) = p;
    }
  }
  __syncthreads();
  if (tid == 0) grcnt[n] = cnt;  // true count (may exceed CAPRL -> select fallback)
}

// ---------------- K3: bf16 MFMA GEMM, NO Cb -> candidates + positives only ----------------
__global__ __launch_bounds__(256) void k_gemm(const u16* __restrict__ fB,
                                              const u16* __restrict__ bankB,
                                              const int* __restrict__ label,
                                              float* __restrict__ gclist,
                                              u32* __restrict__ gccnt,
                                              u16* __restrict__ gpos) {
  __shared__ __align__(16) u16 As[128 * 32];
  __shared__ __align__(16) u16 Bs[128 * 32];
  __shared__ float cstage[128 * CSTG];
  __shared__ u32 ccnt_l[128];
  __shared__ int lab_l[128];
  const int tid = threadIdx.x;
  const int wave = tid >> 6, lane = tid & 63;
  const int bm = blockIdx.x * 128;
  const int bn = blockIdx.y * 128;
  const int wm = (wave & 1) * 64, wn = (wave >> 1) * 64;
  const int m_in = lane & 15;
  const int ks = (lane >> 4) * 8;

  if (tid < 128) { ccnt_l[tid] = 0; lab_l[tid] = label[bm + tid]; }

  f32x4 acc[4][4] = {};

  for (int k0 = 0; k0 < CH; k0 += 32) {
    __syncthreads();
#pragma unroll
    for (int i = 0; i < 2; i++) {
      int u = tid + 256 * i;
      int row = u >> 2;
      int kk = (u & 3) * 8;
      stage16(fB + (size_t)(bm + row) * CH + k0 + kk, As + u * 8);
      int rb = bn + row;
      if (rb >= ROWS) rb = bn;
      stage16(bankB + (size_t)rb * CH + k0 + kk, Bs + u * 8);
    }
    __syncthreads();

    bf16x8 af[4], bf[4];
#pragma unroll
    for (int t4 = 0; t4 < 4; t4++) {
      af[t4] = *(const bf16x8*)(As + (wm + t4 * 16 + m_in) * 32 + ks);
      bf[t4] = *(const bf16x8*)(Bs + (wn + t4 * 16 + m_in) * 32 + ks);
    }
#pragma unroll
    for (int mi = 0; mi < 4; mi++)
#pragma unroll
      for (int ni = 0; ni < 4; ni++)
        acc[mi][ni] = __builtin_amdgcn_mfma_f32_16x16x32_bf16(af[mi], bf[ni], acc[mi][ni], 0, 0, 0);
  }

  const int rr = (lane >> 4) * 4;
  const int cc = lane & 15;
#pragma unroll
  for (int ni = 0; ni < 4; ni++) {
    int ncol = bn + wn + ni * 16 + cc;
    if (ncol >= ROWS) continue;
    int jdiv = ncol / 60;
    int ncolmod = ncol - jdiv * 60;
#pragma unroll
    for (int mi = 0; mi < 4; mi++) {
      int rloc = wm + mi * 16 + rr;
#pragma unroll
      for (int q = 0; q < 4; q++) {
        int rq = rloc + q;
        u16 cw = f2b(acc[mi][ni][q]);
        float c = b2f(cw);
        if (ncolmod == lab_l[rq]) {
          gpos[(size_t)(bm + rq) * MEM + jdiv] = cw;  // positive: direct write
        } else if (c > T1F) {
          u32 slot = atomicAdd(&ccnt_l[rq], 1u);
          if (slot < CSTG) {
            cstage[rq * CSTG + slot] = c;
          } else {  // near-impossible spill path, still exact
            int grow = bm + rq;
            u32 s2 = atomicAdd(&gccnt[grow], 1u);
            if (s2 < CAPCL) gclist[(size_t)grow * CAPCL + s2] = c;
          }
        }
      }
    }
  }
  __syncthreads();
  if (tid < 128) {
    u32 k = umin2(ccnt_l[tid], CSTG);
    if (k) {
      int grow = bm + tid;
      u32 base = atomicAdd(&gccnt[grow], k);
      for (u32 i = 0; i < k; i++) {
        u32 s = base + i;
        if (s < CAPCL) gclist[(size_t)grow * CAPCL + s] = cstage[tid * CSTG + i];
      }
    }
  }
}

// ---------------- block helpers (1024 threads, shfl-based) ----------------
__device__ __forceinline__ u32 scanN(u32 v, u32* tmp, int tid) {
  u32 x = v;
#pragma unroll
  for (int off = 1; off < 64; off <<= 1) {
    u32 y = (u32)__shfl_up((int)x, off, 64);
    if ((tid & 63) >= off) x += y;
  }
  if ((tid & 63) == 63) tmp[tid >> 6] = x;
  __syncthreads();
  if (tid < 64) {
    u32 t = (tid < 16) ? tmp[tid] : 0u;
#pragma unroll
    for (int off = 1; off < 16; off <<= 1) {
      u32 y = (u32)__shfl_up((int)t, off, 64);
      if (tid >= off) t += y;
    }
    if (tid < 16) tmp[tid + 16] = t;
  }
  __syncthreads();
  u32 base = (tid >= 64) ? tmp[16 + (tid >> 6) - 1] : 0u;
  return base + x;
}

__device__ __forceinline__ float redsum1024(float v, float* tmp, int tid) {
#pragma unroll
  for (int off = 32; off > 0; off >>= 1) v += __shfl_xor(v, off, 64);
  if ((tid & 63) == 0) tmp[tid >> 6] = v;
  __syncthreads();
  if (tid < 64) {
    float t = (tid < 16) ? tmp[tid] : 0.f;
#pragma unroll
    for (int off = 8; off > 0; off >>= 1) t += __shfl_xor(t, off, 64);
    if (tid == 0) tmp[0] = t;
  }
  __syncthreads();
  float r = tmp[0];
  __syncthreads();
  return r;
}

__device__ __forceinline__ int binof(float v, float lo, float scale) {
  int b = (int)((v - lo) * scale);
  return b < 0 ? 0 : (b > 2047 ? 2047 : b);
}

// bf16-input fp32-acc dot of f_l (LDS, fp32) with bankB row m
// unroll 4 (not full): keeps VGPR pressure under the 1024-thread budget (R5 spilled)
__device__ float dotm(const float* f_l, const u16* brow) {
  float a0 = 0.f, a1 = 0.f, a2 = 0.f, a3 = 0.f;
#pragma unroll 4
  for (int k = 0; k < CH; k += 8) {
    uint4 w = *(const uint4*)(brow + k);
    float4 fa = *(const float4*)(f_l + k);
    float4 fb = *(const float4*)(f_l + k + 4);
    a0 += fa.x * b2f((u16)w.x) + fa.y * b2f((u16)(w.x >> 16));
    a1 += fa.z * b2f((u16)w.y) + fa.w * b2f((u16)(w.y >> 16));
    a2 += fb.x * b2f((u16)w.z) + fb.y * b2f((u16)(w.z >> 16));
    a3 += fb.z * b2f((u16)w.w) + fb.w * b2f((u16)(w.w >> 16));
  }
  return (a0 + a1) + (a2 + a3);
}

// ---------------- K4: per-row selection + loss (lists only; no Cb) ----------------
__global__ __launch_bounds__(1024) void k_select(const int* __restrict__ label,
                                                 const float* __restrict__ gclist,
                                                 const u32* __restrict__ gccnt,
                                                 const float* __restrict__ grl,
                                                 const u32* __restrict__ grcnt,
                                                 const u16* __restrict__ gpos,
                                                 const u16* __restrict__ fB,
                                                 const u16* __restrict__ bankB,
                                                 const float* __restrict__ rnd,
                                                 float* __restrict__ out) {
  const int n = blockIdx.x;
  const int tid = threadIdx.x;
  const int lab = label[n];

  __shared__ __align__(16) char smem[56576];
  u32* histc = (u32*)(smem);               // 2048
  u32* histr = (u32*)(smem + 8192);        // 2048
  float* cl = (float*)(smem + 16384);      // 4096 (posv aliases)
  float* rl_rv = (float*)(smem + 32768);   // 2048
  u32* rl_mi = (u32*)(smem + 40960);       // 2048
  u32* wl = (u32*)(smem + 49152);          // 512
  float* cb_c = (float*)(smem + 51200);    // 512
  float* rb_r = (float*)(smem + 53248);    // 256
  u32* rb_m = (u32*)(smem + 54272);        // 256
  float* f_l = (float*)(smem + 55296);     // 256
  u32* stmp = (u32*)(smem + 56320);        // 32
  float* fred = (float*)(smem + 56448);    // 16
  u32* ctl = (u32*)(smem + 56512);         // 16
  float* bcf = (float*)(ctl + 8);
  float* posv = cl;

  const u32 Fg = gccnt[n];
  const u32 Gg = grcnt[n];
  const bool cok = (Fg >= NEGN && Fg <= CAPCL);
  const bool rok = (Gg >= NEGN && Gg <= CAPRL);
  const float T1e = cok ? T1F : -1.1f;
  const float sc_c = 2048.0f / (cok ? (1.0625f - T1F) : 2.2f);
  const float sc_r = 2048.0f / (rok ? T0F : 1.0625f);

  for (int i = tid; i < 2048; i += 1024) { histc[i] = 0; histr[i] = 0; }
  if (tid < 16) ctl[tid] = 0;
  if (tid < 256) f_l[tid] = b2f(fB[(size_t)n * CH + tid]);
  __syncthreads();

  // ---- histograms ----
  if (cok) {
    for (u32 i = tid; i < Fg; i += 1024) {
      float c = gclist[(size_t)n * CAPCL + i];
      cl[i] = c;
      atomicAdd(&histc[binof(c, T1e, sc_c)], 1u);
    }
  } else {  // cold exact fallback: recompute all dots
    for (int m = tid; m < ROWS; m += 1024) {
      if (m % 60 == lab) continue;
      float c = b2f(f2b(dotm(f_l, bankB + (size_t)m * CH)));
      atomicAdd(&histc[binof(c, T1e, sc_c)], 1u);
    }
  }
  if (rok) {
    const float* rbase = grl + (size_t)n * CAPRL * 2;
    for (u32 i = tid; i < Gg; i += 1024) {
      float2 p = *(const float2*)(rbase + i * 2);
      rl_rv[i] = p.x;
      rl_mi[i] = __float_as_uint(p.y);
      atomicAdd(&histr[binof(p.x, 0.0f, sc_r)], 1u);
    }
  } else {  // cold fallback: full rnd rescan
    const float* rrow = rnd + (size_t)n * ROWS;
    for (int m = tid; m < ROWS; m += 1024) {
      if (m % 60 == lab) continue;
      atomicAdd(&histr[binof(rrow[m], 0.0f, sc_r)], 1u);
    }
  }
  __syncthreads();

  // ---- boundary c (descending top-NEGN) ----
  u32 fsum = histc[tid * 2] + histc[tid * 2 + 1];
  u32 finc = scanN(fsum, stmp, tid);
  u32 F = stmp[31];
  u32 fexc = finc - fsum;
  u32 tcpos = F - NEGN + 1;
  if (fexc < tcpos && tcpos <= finc) {
    u32 run = fexc;
#pragma unroll
    for (int i = 0; i < 2; i++) {
      u32 h = histc[tid * 2 + i];
      if (run + h >= tcpos) { ctl[2] = (u32)(tid * 2 + i); ctl[3] = F - (run + h); break; }
      run += h;
    }
  }
  // ---- boundary r (ascending bottom-NEGN) ----
  u32 gsum = histr[tid * 2] + histr[tid * 2 + 1];
  u32 ginc = scanN(gsum, stmp, tid);
  u32 gexc = ginc - gsum;
  if (gexc < NEGN && NEGN <= ginc) {
    u32 run = gexc;
#pragma unroll
    for (int i = 0; i < 2; i++) {
      u32 h = histr[tid * 2 + i];
      if (run + h >= NEGN) { ctl[4] = (u32)(tid * 2 + i); ctl[5] = run; break; }
      run += h;
    }
  }
  __syncthreads();
  const u32 b_c = ctl[2], cnt_gt = ctl[3];
  const u32 b_r = ctl[4], cnt_lt = ctl[5];
  const u32 need_c = NEGN - cnt_gt;
  const u32 need_r = NEGN - cnt_lt;

  // ---- phase B: c exp-sums + c-boundary list; r winner list + r-boundary list ----
  float sH = 0.f;
  if (cok) {
    for (u32 i = tid; i < Fg; i += 1024) {
      float c = cl[i];
      u32 b = (u32)binof(c, T1e, sc_c);
      if (b > b_c) sH += expf(c);
      else if (b == b_c) {
        u32 id = atomicAdd(&ctl[0], 1u);
        if (id < 512) cb_c[id] = c;
      }
    }
  } else {
    for (int m = tid; m < ROWS; m += 1024) {
      if (m % 60 == lab) continue;
      float c = b2f(f2b(dotm(f_l, bankB + (size_t)m * CH)));
      u32 b = (u32)binof(c, T1e, sc_c);
      if (b > b_c) sH += expf(c);
      else if (b == b_c) {
        u32 id = atomicAdd(&ctl[0], 1u);
        if (id < 512) cb_c[id] = c;
      }
    }
  }
  if (rok) {
    for (u32 i = tid; i < Gg; i += 1024) {
      float rv = rl_rv[i];
      u32 b = (u32)binof(rv, 0.0f, sc_r);
      if (b < b_r) {
        u32 id = atomicAdd(&ctl[6], 1u);
        wl[id] = rl_mi[i];  // id < cnt_lt <= 511
      } else if (b == b_r) {
        u32 id = atomicAdd(&ctl[1], 1u);
        if (id < 256) { rb_r[id] = rv; rb_m[id] = rl_mi[i]; }
      }
    }
  } else {
    const float* rrow = rnd + (size_t)n * ROWS;
    for (int m = tid; m < ROWS; m += 1024) {
      if (m % 60 == lab) continue;
      float rv = rrow[m];
      u32 b = (u32)binof(rv, 0.0f, sc_r);
      if (b < b_r) {
        u32 id = atomicAdd(&ctl[6], 1u);
        if (id < 512) wl[id] = (u32)m;
      } else if (b == b_r) {
        u32 id = atomicAdd(&ctl[1], 1u);
        if (id < 256) { rb_r[id] = rv; rb_m[id] = (u32)m; }
      }
    }
  }
  __syncthreads();
  float SHsum = redsum1024(sH, fred, tid);

  if (tid == 0) {
    // c boundary bin: take need_c LARGEST values
    float addH = 0.f;
    u32 Lc = umin2(ctl[0], 512u);
    u32 kc = umin2(need_c, Lc);
    for (u32 k = 0; k < kc; k++) {
      int best = 0;
      float bv = -3.0e38f;
      for (u32 i = 0; i < Lc; i++)
        if (cb_c[i] > bv) { bv = cb_c[i]; best = (int)i; }
      cb_c[best] = -3.0e38f;
      addH += expf(bv);
    }
    bcf[0] = addH;
    // rand boundary bin: stable order = (rand value, index) ascending; append winners
    u32 Lr = umin2(ctl[1], 256u);
    for (u32 i = 1; i < Lr; i++) {
      float rv = rb_r[i]; u32 mm = rb_m[i];
      int j = (int)i - 1;
      while (j >= 0 && (rb_r[j] > rv || (rb_r[j] == rv && rb_m[j] > mm))) {
        rb_r[j + 1] = rb_r[j]; rb_m[j + 1] = rb_m[j];
        j--;
      }
      rb_r[j + 1] = rv; rb_m[j + 1] = mm;
    }
    u32 kr = umin2(need_r, Lr);
    u32 base = ctl[6];
    for (u32 i = 0; i < kr; i++)
      if (base + i < 512) wl[base + i] = rb_m[i];
    ctl[7] = umin2(base + kr, 512u);  // winner count (==512 on hot path)
  }
  __syncthreads();

  // ---- winner dots -> S_R ----
  float sR = 0.f;
  if (tid < (int)ctl[7]) {
    u32 m = wl[tid];
    float c = b2f(f2b(dotm(f_l, bankB + (size_t)m * CH)));
    sR = expf(c);
  }
  float SRsum = redsum1024(sR, fred, tid);
  const float S_H = SHsum + bcf[0];
  const float S_R = SRsum;
  __syncthreads();  // cl reads complete before posv (alias) overwrite

  // ---- positives: 684 from gpos, 128 smallest via register bitonic ----
  float v = (tid < MEM) ? b2f(gpos[(size_t)n * MEM + tid]) : INFINITY;
  for (u32 k = 2; k <= 1024; k <<= 1) {
    for (u32 j = k >> 1; j > 0; j >>= 1) {
      bool up = ((tid & k) == 0);
      float pv;
      if (j >= 64) {
        posv[tid] = v;
        __syncthreads();
        pv = posv[tid ^ j];
        __syncthreads();
      } else {
        pv = __shfl_xor(v, (int)j, 64);
      }
      bool lower = ((tid & j) == 0);
      float mn = fminf(v, pv), mx = fmaxf(v, pv);
      v = (lower == up) ? mn : mx;
    }
  }

  float term = 0.f;
  if (tid < POSN) {
    float p = v;
    float e = expf(p);
    term = (p - logf(e + S_H)) + (p - logf(e + S_R));
  }
  float tot = redsum1024(term, fred, tid);
  if (tid == 0) atomicAdd(out, -tot / (float)(BATCHN * 2 * POSN));
}

extern "C" void kernel_launch(void* const* d_in, const int* in_sizes, int n_in,
                              void* d_out, int out_size, void* d_ws, size_t ws_size,
                              hipStream_t stream) {
  const float* f = (const float*)d_in[0];
  const int* label = (const int*)d_in[1];
  const int* enq = (const int*)d_in[2];
  const float* bank = (const float*)d_in[3];
  const float* rnd = (const float*)d_in[5];
  float* out = (float*)d_out;

  // workspace layout (~38.8 MB)
  char* ws = (char*)d_ws;
  u16* bankB = (u16*)ws;                        // 21,012,480
  u16* fB = (u16*)(ws + 21012480);              //    262,144
  float* gclist = (float*)(ws + 21274624);      // 512*4096*4 = 8,388,608
  float* grl = (float*)(ws + 29663232);         // 512*2048*8 = 8,388,608
  u16* gpos = (u16*)(ws + 38051840);            // 512*684*2  =   700,416
  u32* gccnt = (u32*)(ws + 38752256);           // 2048
  u32* grcnt = (u32*)(ws + 38754304);           // 2048

  k_prep<<<dim3(5195), dim3(256), 0, stream>>>(bank, f, enq, bankB, fB, gccnt, out);
  k_rfilter<<<dim3(BATCHN), dim3(1024), 0, stream>>>(rnd, label, grl, grcnt);
  k_gemm<<<dim3(4, 321), dim3(256), 0, stream>>>(fB, bankB, label, gclist, gccnt, gpos);
  k_select<<<dim3(BATCHN), dim3(1024), 0, stream>>>(label, gclist, gccnt, grl, grcnt, gpos,
                                                    fB, bankB, rnd, out);
}